// Round 1
// baseline (5075.233 us; speedup 1.0000x reference)
//
#include <hip/hip_runtime.h>
#include <hip/hip_bf16.h>

#define HD 2560
#define NEXP 16
#define TI 1536
#define VI 512
#define SI 3072
#define NTOK 4096
#define CAP 4096

typedef float f4 __attribute__((ext_vector_type(4)));
typedef unsigned int u32x2 __attribute__((ext_vector_type(2)));
typedef short s16x8 __attribute__((ext_vector_type(8)));

// pack two f32 -> two bf16 (round-to-nearest via +0x8000, then byte-perm)
__device__ __forceinline__ unsigned int pkbf(float lo, float hi) {
  unsigned int ul = __builtin_bit_cast(unsigned int, lo) + 0x8000u;
  unsigned int uh = __builtin_bit_cast(unsigned int, hi) + 0x8000u;
  return __builtin_amdgcn_perm(uh, ul, 0x07060302u);
}
__device__ __forceinline__ unsigned short bf1(float x) {
  unsigned int u = __builtin_bit_cast(unsigned int, x);
  return (unsigned short)((u + 0x7fffu + ((u >> 16) & 1u)) >> 16);
}

// ---------------------------------------------------------------- zero counts
__global__ void zero_counts(int* counts) {
  if (threadIdx.x < 32) counts[threadIdx.x] = 0;
}

// ---------------------------------------------------------------- router
__global__ __launch_bounds__(256, 2)
void router_kernel(const float* __restrict__ X,
                   const int* __restrict__ tti,
                   const float* __restrict__ tw, const float* __restrict__ tb,
                   const float* __restrict__ vw, const float* __restrict__ vb,
                   float* __restrict__ logits_out,
                   int* __restrict__ counts,
                   int* __restrict__ disp,
                   float* __restrict__ dispw)
{
  const int lane = threadIdx.x & 63;
  const int t = blockIdx.x * 4 + (threadIdx.x >> 6);
  const bool vis = tti[t] != 0;
  const float* w = vis ? vw : tw;
  const float* bias = vis ? vb : tb;
  const int base = vis ? NEXP : 0;

  f4 xr[10];
#pragma unroll
  for (int i = 0; i < 10; ++i)
    xr[i] = *(const f4*)(X + (unsigned long long)t * HD + (lane + 64 * i) * 4);

  float l[NEXP];
#pragma unroll
  for (int e = 0; e < NEXP; ++e) {
    const float* wr = w + e * HD;
    float a = 0.f;
#pragma unroll
    for (int i = 0; i < 10; ++i) {
      f4 wv = *(const f4*)(wr + (lane + 64 * i) * 4);
      a += xr[i].x * wv.x; a += xr[i].y * wv.y;
      a += xr[i].z * wv.z; a += xr[i].w * wv.w;
    }
#pragma unroll
    for (int off = 32; off > 0; off >>= 1) a += __shfl_xor(a, off);
    l[e] = a;
  }

  float mx = l[0];
#pragma unroll
  for (int e = 1; e < NEXP; ++e) mx = fmaxf(mx, l[e]);
  float p[NEXP]; float sum = 0.f;
#pragma unroll
  for (int e = 0; e < NEXP; ++e) { p[e] = expf(l[e] - mx); sum += p[e]; }
  float inv = 1.f / sum;
  float c[NEXP];
#pragma unroll
  for (int e = 0; e < NEXP; ++e) { p[e] *= inv; c[e] = p[e] + bias[e]; }

  int sel[6]; float selp[6]; float wsum = 0.f;
#pragma unroll
  for (int r = 0; r < 6; ++r) {
    float best = -1e30f; int bi = 0;
#pragma unroll
    for (int e = 0; e < NEXP; ++e) if (c[e] > best) { best = c[e]; bi = e; }
    float pb = 0.f;
#pragma unroll
    for (int e = 0; e < NEXP; ++e) if (e == bi) { pb = p[e]; c[e] = -1e30f; }
    sel[r] = bi; selp[r] = pb; wsum += pb;
  }
  if (wsum < 1e-12f) wsum = 1e-12f;

  if (lane < NEXP) {
    float ov = l[0];
#pragma unroll
    for (int e = 1; e < NEXP; ++e) if (lane == e) ov = l[e];
    logits_out[(unsigned long long)t * NEXP + lane] = ov;
  }
  if (lane < 6) {
    int my_e = sel[0]; float my_p = selp[0];
#pragma unroll
    for (int r = 1; r < 6; ++r) if (lane == r) { my_e = sel[r]; my_p = selp[r]; }
    int slot = atomicAdd(&counts[base + my_e], 1);
    if (slot < CAP) {
      disp[(base + my_e) * CAP + slot] = (t << 3) | lane;
      dispw[(base + my_e) * CAP + slot] = my_p / wsum;
    }
  }
}

// ---------------------------------------------------------------- up (dual GEMM + silu*u)
// C_g = X*Wg, C_u = X*Wu over 128x64 logical cols; act[loc][col] = silu(g)*u (bf16)
template<bool GATHER>
__global__ __launch_bounds__(256, 3)
void up_kernel(const float* __restrict__ X,
               const float* __restrict__ Wg0,
               const float* __restrict__ Wu0,
               const int ldb, const unsigned long long wstride,
               const int* __restrict__ counts,
               const int* __restrict__ disp,
               unsigned short* __restrict__ act,
               const int act_ld)
{
  const int e = blockIdx.z;
  const int M = GATHER ? min(counts[e], CAP) : NTOK;
  const int m0 = blockIdx.y * 128;
  if (m0 >= M) return;
  const int n0 = blockIdx.x * 64;
  const float* Wg = Wg0 + (unsigned long long)e * wstride;
  const float* Wu = Wu0 + (unsigned long long)e * wstride;

  __shared__ unsigned short lA[128 * 72];
  __shared__ unsigned short lB[128 * 72];
  __shared__ int s_loc[128];
  __shared__ int s_tok[128];

  const int tid = threadIdx.x;
  if (tid < 128) {
    int row = m0 + tid;
    int tok = 0, loc = -1;
    if (row < M) {
      if (GATHER) {
        int entry = disp[e * CAP + row];
        tok = entry >> 3;
        loc = tok * 6 + (entry & 7);
      } else { tok = row; loc = row; }
    }
    s_tok[tid] = tok; s_loc[tid] = loc;
  }
  __syncthreads();

  const int qk = tid & 15;          // A: k-quad (k = qk*4)
  const int ar0 = tid >> 4;         // A: row base 0..15
  int aoff[8];
#pragma unroll
  for (int p = 0; p < 8; ++p) aoff[p] = s_tok[ar0 + p * 16] * HD;

  const int cq = tid & 31;          // B: col within 32-group
  const int kqb = tid >> 5;         // B: k-quad base 0..7
  const float* bbase[4];
#pragma unroll
  for (int c = 0; c < 4; ++c) {
    int r = c * 32 + cq;            // LDS row: 0..63 = g cols, 64..127 = u cols
    bbase[c] = (r < 64) ? (Wg + n0 + r) : (Wu + n0 + (r - 64));
  }

  f4 acc[4][4];
  f4 zz = {0.f, 0.f, 0.f, 0.f};
#pragma unroll
  for (int i = 0; i < 4; ++i)
#pragma unroll
    for (int j = 0; j < 4; ++j) acc[i][j] = zz;

  const int lane = tid & 63;
  const int wm = tid >> 7;
  const int wn = (tid >> 6) & 1;
  const int l16 = lane & 15;
  const int kq8 = (lane >> 4) * 8;

  for (int k0 = 0; k0 < HD; k0 += 64) {
#pragma unroll
    for (int p = 0; p < 8; ++p) {
      f4 v = *(const f4*)(X + aoff[p] + k0 + qk * 4);
      u32x2 wv; wv.x = pkbf(v.x, v.y); wv.y = pkbf(v.z, v.w);
      *(u32x2*)&lA[(ar0 + p * 16) * 72 + qk * 4] = wv;
    }
#pragma unroll
    for (int h = 0; h < 2; ++h) {
      const int k = kqb * 4 + h * 32;
#pragma unroll
      for (int c = 0; c < 4; ++c) {
        const float* bp = bbase[c] + (unsigned long long)(k0 + k) * ldb;
        float v0 = bp[0];
        float v1 = bp[ldb];
        float v2 = bp[2 * ldb];
        float v3 = bp[3 * ldb];
        u32x2 wv; wv.x = pkbf(v0, v1); wv.y = pkbf(v2, v3);
        *(u32x2*)&lB[(c * 32 + cq) * 72 + k] = wv;
      }
    }
    __syncthreads();
#pragma unroll
    for (int kc = 0; kc < 2; ++kc) {
      s16x8 a[4], b[4];
#pragma unroll
      for (int mi = 0; mi < 4; ++mi)
        a[mi] = *(const s16x8*)&lA[(wm * 64 + mi * 16 + l16) * 72 + kc * 32 + kq8];
#pragma unroll
      for (int cf = 0; cf < 4; ++cf) {
        int brow = ((cf >= 2) ? 64 : 0) + wn * 32 + (cf & 1) * 16 + l16;
        b[cf] = *(const s16x8*)&lB[brow * 72 + kc * 32 + kq8];
      }
#pragma unroll
      for (int mi = 0; mi < 4; ++mi)
#pragma unroll
        for (int cf = 0; cf < 4; ++cf)
          acc[mi][cf] = __builtin_amdgcn_mfma_f32_16x16x32_bf16(a[mi], b[cf], acc[mi][cf], 0, 0, 0);
    }
    __syncthreads();
  }

#pragma unroll
  for (int mi = 0; mi < 4; ++mi)
#pragma unroll
    for (int jf = 0; jf < 2; ++jf)
#pragma unroll
      for (int r = 0; r < 4; ++r) {
        int rb = wm * 64 + mi * 16 + (lane >> 4) * 4 + r;
        int loc = s_loc[rb];
        if (loc >= 0) {
          float g = acc[mi][jf][r];
          float u = acc[mi][jf + 2][r];
          float s = g / (1.f + __expf(-g));
          int col = n0 + wn * 32 + jf * 16 + l16;
          act[(unsigned long long)loc * act_ld + col] = bf1(s * u);
        }
      }
}

// ---------------------------------------------------------------- down GEMM (+ scatter)
template<bool SCATTER>
__global__ __launch_bounds__(256, 3)
void down_kernel(const unsigned short* __restrict__ Act, const int ldA,
                 const float* __restrict__ W0, const unsigned long long wstride,
                 const int K,
                 const int* __restrict__ counts,
                 const int* __restrict__ disp,
                 const float* __restrict__ dispw,
                 float* __restrict__ Out)
{
  const int e = blockIdx.z;
  const int M = SCATTER ? min(counts[e], CAP) : NTOK;
  const int m0 = blockIdx.y * 128;
  if (m0 >= M) return;
  const int n0 = blockIdx.x * 128;
  const float* W = W0 + (unsigned long long)e * wstride;

  __shared__ unsigned short lA[128 * 72];
  __shared__ unsigned short lB[128 * 72];
  __shared__ int s_tok[128];
  __shared__ float s_w[128];
  __shared__ int s_loc[128];

  const int tid = threadIdx.x;
  if (tid < 128) {
    int row = m0 + tid;
    int tok = -1, loc = 0; float w = 0.f;
    if (row < M) {
      if (SCATTER) {
        int entry = disp[e * CAP + row];
        tok = entry >> 3; loc = tok * 6 + (entry & 7);
        w = dispw[e * CAP + row];
      } else { tok = row; loc = row; w = 1.f; }
    }
    s_tok[tid] = tok; s_loc[tid] = loc; s_w[tid] = w;
  }
  __syncthreads();

  const int oct = tid & 7;          // A: k-octet (k = oct*8), bf16 direct copy
  const int ar0 = tid >> 3;         // rows 0..31, 4 passes
  unsigned int aoff[4];
#pragma unroll
  for (int p = 0; p < 4; ++p)
    aoff[p] = (unsigned int)s_loc[ar0 + p * 32] * (unsigned int)ldA;

  const int cq = tid & 31;
  const int kqb = tid >> 5;

  f4 acc[4][4];
  f4 zz = {0.f, 0.f, 0.f, 0.f};
#pragma unroll
  for (int i = 0; i < 4; ++i)
#pragma unroll
    for (int j = 0; j < 4; ++j) acc[i][j] = zz;

  const int lane = tid & 63;
  const int wm = tid >> 7;
  const int wn = (tid >> 6) & 1;
  const int l16 = lane & 15;
  const int kq8 = (lane >> 4) * 8;

  for (int k0 = 0; k0 < K; k0 += 64) {
#pragma unroll
    for (int p = 0; p < 4; ++p) {
      f4 v = *(const f4*)(Act + aoff[p] + k0 + oct * 8);
      *(f4*)&lA[(ar0 + p * 32) * 72 + oct * 8] = v;
    }
#pragma unroll
    for (int h = 0; h < 2; ++h) {
      const int k = kqb * 4 + h * 32;
#pragma unroll
      for (int c = 0; c < 4; ++c) {
        const float* bp = W + (unsigned long long)(k0 + k) * HD + n0 + c * 32 + cq;
        float v0 = bp[0];
        float v1 = bp[HD];
        float v2 = bp[2 * HD];
        float v3 = bp[3 * HD];
        u32x2 wv; wv.x = pkbf(v0, v1); wv.y = pkbf(v2, v3);
        *(u32x2*)&lB[(c * 32 + cq) * 72 + k] = wv;
      }
    }
    __syncthreads();
#pragma unroll
    for (int kc = 0; kc < 2; ++kc) {
      s16x8 a[4], b[4];
#pragma unroll
      for (int mi = 0; mi < 4; ++mi)
        a[mi] = *(const s16x8*)&lA[(wm * 64 + mi * 16 + l16) * 72 + kc * 32 + kq8];
#pragma unroll
      for (int cf = 0; cf < 4; ++cf)
        b[cf] = *(const s16x8*)&lB[(wn * 64 + cf * 16 + l16) * 72 + kc * 32 + kq8];
#pragma unroll
      for (int mi = 0; mi < 4; ++mi)
#pragma unroll
        for (int cf = 0; cf < 4; ++cf)
          acc[mi][cf] = __builtin_amdgcn_mfma_f32_16x16x32_bf16(a[mi], b[cf], acc[mi][cf], 0, 0, 0);
    }
    __syncthreads();
  }

#pragma unroll
  for (int mi = 0; mi < 4; ++mi)
#pragma unroll
    for (int cf = 0; cf < 4; ++cf)
#pragma unroll
      for (int r = 0; r < 4; ++r) {
        int rb = wm * 64 + mi * 16 + (lane >> 4) * 4 + r;
        int col = n0 + wn * 64 + cf * 16 + l16;
        if (SCATTER) {
          int tok = s_tok[rb];
          if (tok >= 0)
            unsafeAtomicAdd(Out + (unsigned long long)tok * HD + col,
                            acc[mi][cf][r] * s_w[rb]);
        } else {
          Out[(unsigned long long)(m0 + rb) * HD + col] = acc[mi][cf][r];
        }
      }
}

// ---------------------------------------------------------------- launch
extern "C" void kernel_launch(void* const* d_in, const int* in_sizes, int n_in,
                              void* d_out, int out_size, void* d_ws, size_t ws_size,
                              hipStream_t stream)
{
  const float* X    = (const float*)d_in[0];
  const int*   tti  = (const int*)d_in[1];
  const float* t_rw = (const float*)d_in[2];
  const float* t_rb = (const float*)d_in[3];
  const float* t_gu = (const float*)d_in[4];
  const float* t_dn = (const float*)d_in[5];
  const float* v_rw = (const float*)d_in[6];
  const float* v_rb = (const float*)d_in[7];
  const float* v_gu = (const float*)d_in[8];
  const float* v_dn = (const float*)d_in[9];
  const float* s_g  = (const float*)d_in[10];
  const float* s_u  = (const float*)d_in[11];
  const float* s_d  = (const float*)d_in[12];

  float* out_final  = (float*)d_out;
  float* out_logits = out_final + (size_t)NTOK * HD;

  char* ws = (char*)d_ws;
  int*   counts = (int*)ws;                                   // 32 ints
  int*   disp   = (int*)(ws + 256);                           // [2][16][CAP]
  float* dispw  = (float*)(ws + 256 + 2 * NEXP * CAP * 4);    // [2][16][CAP]
  unsigned short* act = (unsigned short*)(ws + 256 + 4 * NEXP * CAP * 4 + 256);
  // act buffer reused sequentially: shared (4096*3072), text (24576*1536), vis (24576*512)

  dim3 blk(256);

  zero_counts<<<1, 64, 0, stream>>>(counts);
  router_kernel<<<dim3(NTOK / 4), blk, 0, stream>>>(
      X, tti, t_rw, t_rb, v_rw, v_rb, out_logits, counts, disp, dispw);

  // shared expert: writes (initializes) out_final
  up_kernel<false><<<dim3(SI / 64, NTOK / 128, 1), blk, 0, stream>>>(
      X, s_g, s_u, SI, 0ULL, nullptr, nullptr, act, SI);
  down_kernel<false><<<dim3(HD / 128, NTOK / 128, 1), blk, 0, stream>>>(
      act, SI, s_d, 0ULL, SI, nullptr, nullptr, nullptr, out_final);

  // text experts (modality 0) — atomic accumulate into out_final
  up_kernel<true><<<dim3(TI / 64, CAP / 128, NEXP), blk, 0, stream>>>(
      X, t_gu, t_gu + TI, 2 * TI, (unsigned long long)HD * 2 * TI,
      counts, disp, act, TI);
  down_kernel<true><<<dim3(HD / 128, CAP / 128, NEXP), blk, 0, stream>>>(
      act, TI, t_dn, (unsigned long long)TI * HD, TI,
      counts, disp, dispw, out_final);

  // vis experts (modality 1)
  up_kernel<true><<<dim3(VI / 64, CAP / 128, NEXP), blk, 0, stream>>>(
      X, v_gu, v_gu + VI, 2 * VI, (unsigned long long)HD * 2 * VI,
      counts + NEXP, disp + NEXP * CAP, act, VI);
  down_kernel<true><<<dim3(HD / 128, CAP / 128, NEXP), blk, 0, stream>>>(
      act, VI, v_dn, (unsigned long long)VI * HD, VI,
      counts + NEXP, disp + NEXP * CAP, dispw + NEXP * CAP, out_final);

  (void)in_sizes; (void)n_in; (void)out_size; (void)ws_size;
}

// Round 2
// 3357.586 us; speedup vs baseline: 1.5116x; 1.5116x over previous
//
#include <hip/hip_runtime.h>
#include <hip/hip_bf16.h>

#define HD 2560
#define NEXP 16
#define TI 1536
#define VI 512
#define SI 3072
#define NTOK 4096
#define CAP 4096

typedef float f4 __attribute__((ext_vector_type(4)));
typedef unsigned int u32x2 __attribute__((ext_vector_type(2)));
typedef short s16x8 __attribute__((ext_vector_type(8)));

// pack two f32 -> two bf16 (round-to-nearest via +0x8000, then byte-perm)
__device__ __forceinline__ unsigned int pkbf(float lo, float hi) {
  unsigned int ul = __builtin_bit_cast(unsigned int, lo) + 0x8000u;
  unsigned int uh = __builtin_bit_cast(unsigned int, hi) + 0x8000u;
  return __builtin_amdgcn_perm(uh, ul, 0x07060302u);
}
__device__ __forceinline__ unsigned short bf1(float x) {
  unsigned int u = __builtin_bit_cast(unsigned int, x);
  return (unsigned short)((u + 0x7fffu + ((u >> 16) & 1u)) >> 16);
}

// ---------------------------------------------------------------- zero counts
__global__ void zero_counts(int* counts) {
  if (threadIdx.x < 32) counts[threadIdx.x] = 0;
}

// ---------------------------------------------------------------- router
__global__ __launch_bounds__(256, 2)
void router_kernel(const float* __restrict__ X,
                   const int* __restrict__ tti,
                   const float* __restrict__ tw, const float* __restrict__ tb,
                   const float* __restrict__ vw, const float* __restrict__ vb,
                   float* __restrict__ logits_out,
                   int* __restrict__ counts,
                   int* __restrict__ disp,
                   float* __restrict__ dispw)
{
  const int lane = threadIdx.x & 63;
  const int t = blockIdx.x * 4 + (threadIdx.x >> 6);
  const bool vis = tti[t] != 0;
  const float* w = vis ? vw : tw;
  const float* bias = vis ? vb : tb;
  const int base = vis ? NEXP : 0;

  f4 xr[10];
#pragma unroll
  for (int i = 0; i < 10; ++i)
    xr[i] = *(const f4*)(X + (unsigned long long)t * HD + (lane + 64 * i) * 4);

  float l[NEXP];
#pragma unroll
  for (int e = 0; e < NEXP; ++e) {
    const float* wr = w + e * HD;
    float a = 0.f;
#pragma unroll
    for (int i = 0; i < 10; ++i) {
      f4 wv = *(const f4*)(wr + (lane + 64 * i) * 4);
      a += xr[i].x * wv.x; a += xr[i].y * wv.y;
      a += xr[i].z * wv.z; a += xr[i].w * wv.w;
    }
#pragma unroll
    for (int off = 32; off > 0; off >>= 1) a += __shfl_xor(a, off);
    l[e] = a;
  }

  float mx = l[0];
#pragma unroll
  for (int e = 1; e < NEXP; ++e) mx = fmaxf(mx, l[e]);
  float p[NEXP]; float sum = 0.f;
#pragma unroll
  for (int e = 0; e < NEXP; ++e) { p[e] = expf(l[e] - mx); sum += p[e]; }
  float inv = 1.f / sum;
  float c[NEXP];
#pragma unroll
  for (int e = 0; e < NEXP; ++e) { p[e] *= inv; c[e] = p[e] + bias[e]; }

  int sel[6]; float selp[6]; float wsum = 0.f;
#pragma unroll
  for (int r = 0; r < 6; ++r) {
    float best = -1e30f; int bi = 0;
#pragma unroll
    for (int e = 0; e < NEXP; ++e) if (c[e] > best) { best = c[e]; bi = e; }
    float pb = 0.f;
#pragma unroll
    for (int e = 0; e < NEXP; ++e) if (e == bi) { pb = p[e]; c[e] = -1e30f; }
    sel[r] = bi; selp[r] = pb; wsum += pb;
  }
  if (wsum < 1e-12f) wsum = 1e-12f;

  if (lane < NEXP) {
    float ov = l[0];
#pragma unroll
    for (int e = 1; e < NEXP; ++e) if (lane == e) ov = l[e];
    logits_out[(unsigned long long)t * NEXP + lane] = ov;
  }
  if (lane < 6) {
    int my_e = sel[0]; float my_p = selp[0];
#pragma unroll
    for (int r = 1; r < 6; ++r) if (lane == r) { my_e = sel[r]; my_p = selp[r]; }
    int slot = atomicAdd(&counts[base + my_e], 1);
    if (slot < CAP) {
      disp[(base + my_e) * CAP + slot] = (t << 3) | lane;
      dispw[(base + my_e) * CAP + slot] = my_p / wsum;
    }
  }
}

// ---------------------------------------------------------------- up (dual GEMM + silu*u)
// C_g = X*Wg, C_u = X*Wu over 128x64 logical cols; act[loc][col] = silu(g)*u (bf16)
template<bool GATHER>
__global__ __launch_bounds__(256, 4)
void up_kernel(const float* __restrict__ X,
               const float* __restrict__ Wg0,
               const float* __restrict__ Wu0,
               const int ldb, const unsigned long long wstride,
               const int* __restrict__ counts,
               const int* __restrict__ disp,
               unsigned short* __restrict__ act,
               const int act_ld)
{
  const int e = blockIdx.z;
  const int M = GATHER ? min(counts[e], CAP) : NTOK;
  const int m0 = blockIdx.y * 128;
  if (m0 >= M) return;
  const int n0 = blockIdx.x * 64;
  const float* Wg = Wg0 + (unsigned long long)e * wstride;
  const float* Wu = Wu0 + (unsigned long long)e * wstride;

  __shared__ unsigned short lA[128 * 72];
  __shared__ unsigned short lB[128 * 72];
  __shared__ int s_loc[128];
  __shared__ int s_tok[128];

  const int tid = threadIdx.x;
  if (tid < 128) {
    int row = m0 + tid;
    int tok = 0, loc = -1;
    if (row < M) {
      if (GATHER) {
        int entry = disp[e * CAP + row];
        tok = entry >> 3;
        loc = tok * 6 + (entry & 7);
      } else { tok = row; loc = row; }
    }
    s_tok[tid] = tok; s_loc[tid] = loc;
  }
  __syncthreads();

  const int qk = tid & 15;          // A: k-quad (k = qk*4)
  const int ar0 = tid >> 4;         // A: row base 0..15
  int aoff[8];
#pragma unroll
  for (int p = 0; p < 8; ++p) aoff[p] = s_tok[ar0 + p * 16] * HD;

  // B staging: thread owns 4n x 4k blocks. ng in [0,32): LDS rows ng*4..+3.
  // Rows 0..63 = Wg cols n0..n0+63, rows 64..127 = Wu cols n0..n0+63.
  const int ng = tid & 31;
  const int kq = tid >> 5;          // 0..7
  const float* bp0 = (ng < 16) ? (Wg + n0 + ng * 4) : (Wu + n0 + (ng - 16) * 4);

  f4 acc[4][4];
  f4 zz = {0.f, 0.f, 0.f, 0.f};
#pragma unroll
  for (int i = 0; i < 4; ++i)
#pragma unroll
    for (int j = 0; j < 4; ++j) acc[i][j] = zz;

  const int lane = tid & 63;
  const int wm = tid >> 7;
  const int wn = (tid >> 6) & 1;
  const int l16 = lane & 15;
  const int kq8 = (lane >> 4) * 8;

  for (int k0 = 0; k0 < HD; k0 += 64) {
#pragma unroll
    for (int p = 0; p < 8; ++p) {
      f4 v = *(const f4*)(X + aoff[p] + k0 + qk * 4);
      u32x2 wv; wv.x = pkbf(v.x, v.y); wv.y = pkbf(v.z, v.w);
      *(u32x2*)&lA[(ar0 + p * 16) * 72 + qk * 4] = wv;
    }
#pragma unroll
    for (int h = 0; h < 2; ++h) {
      const int k = k0 + kq * 4 + h * 32;
      const float* bp = bp0 + (unsigned long long)k * ldb;
      f4 r0 = *(const f4*)(bp);
      f4 r1 = *(const f4*)(bp + ldb);
      f4 r2 = *(const f4*)(bp + 2 * ldb);
      f4 r3 = *(const f4*)(bp + 3 * ldb);
#pragma unroll
      for (int n = 0; n < 4; ++n) {
        u32x2 wv; wv.x = pkbf(r0[n], r1[n]); wv.y = pkbf(r2[n], r3[n]);
        *(u32x2*)&lB[(ng * 4 + n) * 72 + h * 32 + kq * 4] = wv;
      }
    }
    __syncthreads();
#pragma unroll
    for (int kc = 0; kc < 2; ++kc) {
      s16x8 a[4], b[4];
#pragma unroll
      for (int mi = 0; mi < 4; ++mi)
        a[mi] = *(const s16x8*)&lA[(wm * 64 + mi * 16 + l16) * 72 + kc * 32 + kq8];
#pragma unroll
      for (int cf = 0; cf < 4; ++cf) {
        int brow = ((cf >= 2) ? 64 : 0) + wn * 32 + (cf & 1) * 16 + l16;
        b[cf] = *(const s16x8*)&lB[brow * 72 + kc * 32 + kq8];
      }
#pragma unroll
      for (int mi = 0; mi < 4; ++mi)
#pragma unroll
        for (int cf = 0; cf < 4; ++cf)
          acc[mi][cf] = __builtin_amdgcn_mfma_f32_16x16x32_bf16(a[mi], b[cf], acc[mi][cf], 0, 0, 0);
    }
    __syncthreads();
  }

#pragma unroll
  for (int mi = 0; mi < 4; ++mi)
#pragma unroll
    for (int jf = 0; jf < 2; ++jf)
#pragma unroll
      for (int r = 0; r < 4; ++r) {
        int rb = wm * 64 + mi * 16 + (lane >> 4) * 4 + r;
        int loc = s_loc[rb];
        if (loc >= 0) {
          float g = acc[mi][jf][r];
          float u = acc[mi][jf + 2][r];
          float s = g / (1.f + __expf(-g));
          int col = n0 + wn * 32 + jf * 16 + l16;
          act[(unsigned long long)loc * act_ld + col] = bf1(s * u);
        }
      }
}

// ---------------------------------------------------------------- down GEMM (+ scatter)
template<bool SCATTER>
__global__ __launch_bounds__(256, 4)
void down_kernel(const unsigned short* __restrict__ Act, const int ldA,
                 const float* __restrict__ W0, const unsigned long long wstride,
                 const int K,
                 const int* __restrict__ counts,
                 const int* __restrict__ disp,
                 const float* __restrict__ dispw,
                 float* __restrict__ Out)
{
  const int e = blockIdx.z;
  const int M = SCATTER ? min(counts[e], CAP) : NTOK;
  const int m0 = blockIdx.y * 128;
  if (m0 >= M) return;
  const int n0 = blockIdx.x * 128;
  const float* W = W0 + (unsigned long long)e * wstride;

  __shared__ unsigned short lA[128 * 72];
  __shared__ unsigned short lB[128 * 72];
  __shared__ int s_tok[128];
  __shared__ float s_w[128];
  __shared__ int s_loc[128];

  const int tid = threadIdx.x;
  if (tid < 128) {
    int row = m0 + tid;
    int tok = -1, loc = 0; float w = 0.f;
    if (row < M) {
      if (SCATTER) {
        int entry = disp[e * CAP + row];
        tok = entry >> 3; loc = tok * 6 + (entry & 7);
        w = dispw[e * CAP + row];
      } else { tok = row; loc = row; w = 1.f; }
    }
    s_tok[tid] = tok; s_loc[tid] = loc; s_w[tid] = w;
  }
  __syncthreads();

  const int oct = tid & 7;          // A: k-octet (k = oct*8), bf16 direct copy
  const int ar0 = tid >> 3;         // rows 0..31, 4 passes
  unsigned int aoff[4];
#pragma unroll
  for (int p = 0; p < 4; ++p)
    aoff[p] = (unsigned int)s_loc[ar0 + p * 32] * (unsigned int)ldA;

  // B staging: thread owns 4n x 4k blocks; LDS rows = n (128), cols = k (64)
  const int ng = tid & 31;
  const int kq = tid >> 5;
  const float* bp0 = W + n0 + ng * 4;

  f4 acc[4][4];
  f4 zz = {0.f, 0.f, 0.f, 0.f};
#pragma unroll
  for (int i = 0; i < 4; ++i)
#pragma unroll
    for (int j = 0; j < 4; ++j) acc[i][j] = zz;

  const int lane = tid & 63;
  const int wm = tid >> 7;
  const int wn = (tid >> 6) & 1;
  const int l16 = lane & 15;
  const int kq8 = (lane >> 4) * 8;

  for (int k0 = 0; k0 < K; k0 += 64) {
#pragma unroll
    for (int p = 0; p < 4; ++p) {
      f4 v = *(const f4*)(Act + aoff[p] + k0 + oct * 8);
      *(f4*)&lA[(ar0 + p * 32) * 72 + oct * 8] = v;
    }
#pragma unroll
    for (int h = 0; h < 2; ++h) {
      const int k = k0 + kq * 4 + h * 32;
      const float* bp = bp0 + (unsigned long long)k * HD;
      f4 r0 = *(const f4*)(bp);
      f4 r1 = *(const f4*)(bp + HD);
      f4 r2 = *(const f4*)(bp + 2 * HD);
      f4 r3 = *(const f4*)(bp + 3 * HD);
#pragma unroll
      for (int n = 0; n < 4; ++n) {
        u32x2 wv; wv.x = pkbf(r0[n], r1[n]); wv.y = pkbf(r2[n], r3[n]);
        *(u32x2*)&lB[(ng * 4 + n) * 72 + h * 32 + kq * 4] = wv;
      }
    }
    __syncthreads();
#pragma unroll
    for (int kc = 0; kc < 2; ++kc) {
      s16x8 a[4], b[4];
#pragma unroll
      for (int mi = 0; mi < 4; ++mi)
        a[mi] = *(const s16x8*)&lA[(wm * 64 + mi * 16 + l16) * 72 + kc * 32 + kq8];
#pragma unroll
      for (int cf = 0; cf < 4; ++cf)
        b[cf] = *(const s16x8*)&lB[(wn * 64 + cf * 16 + l16) * 72 + kc * 32 + kq8];
#pragma unroll
      for (int mi = 0; mi < 4; ++mi)
#pragma unroll
        for (int cf = 0; cf < 4; ++cf)
          acc[mi][cf] = __builtin_amdgcn_mfma_f32_16x16x32_bf16(a[mi], b[cf], acc[mi][cf], 0, 0, 0);
    }
    __syncthreads();
  }

#pragma unroll
  for (int mi = 0; mi < 4; ++mi)
#pragma unroll
    for (int cf = 0; cf < 4; ++cf)
#pragma unroll
      for (int r = 0; r < 4; ++r) {
        int rb = wm * 64 + mi * 16 + (lane >> 4) * 4 + r;
        int col = n0 + wn * 64 + cf * 16 + l16;
        if (SCATTER) {
          int tok = s_tok[rb];
          if (tok >= 0)
            unsafeAtomicAdd(Out + (unsigned long long)tok * HD + col,
                            acc[mi][cf][r] * s_w[rb]);
        } else {
          Out[(unsigned long long)(m0 + rb) * HD + col] = acc[mi][cf][r];
        }
      }
}

// ---------------------------------------------------------------- launch
extern "C" void kernel_launch(void* const* d_in, const int* in_sizes, int n_in,
                              void* d_out, int out_size, void* d_ws, size_t ws_size,
                              hipStream_t stream)
{
  const float* X    = (const float*)d_in[0];
  const int*   tti  = (const int*)d_in[1];
  const float* t_rw = (const float*)d_in[2];
  const float* t_rb = (const float*)d_in[3];
  const float* t_gu = (const float*)d_in[4];
  const float* t_dn = (const float*)d_in[5];
  const float* v_rw = (const float*)d_in[6];
  const float* v_rb = (const float*)d_in[7];
  const float* v_gu = (const float*)d_in[8];
  const float* v_dn = (const float*)d_in[9];
  const float* s_g  = (const float*)d_in[10];
  const float* s_u  = (const float*)d_in[11];
  const float* s_d  = (const float*)d_in[12];

  float* out_final  = (float*)d_out;
  float* out_logits = out_final + (size_t)NTOK * HD;

  char* ws = (char*)d_ws;
  int*   counts = (int*)ws;                                   // 32 ints
  int*   disp   = (int*)(ws + 256);                           // [2][16][CAP]
  float* dispw  = (float*)(ws + 256 + 2 * NEXP * CAP * 4);    // [2][16][CAP]
  unsigned short* act = (unsigned short*)(ws + 256 + 4 * NEXP * CAP * 4 + 256);
  // act buffer reused sequentially: shared (4096*3072), text (24576*1536), vis (24576*512)

  dim3 blk(256);

  zero_counts<<<1, 64, 0, stream>>>(counts);
  router_kernel<<<dim3(NTOK / 4), blk, 0, stream>>>(
      X, tti, t_rw, t_rb, v_rw, v_rb, out_logits, counts, disp, dispw);

  // shared expert: writes (initializes) out_final
  up_kernel<false><<<dim3(SI / 64, NTOK / 128, 1), blk, 0, stream>>>(
      X, s_g, s_u, SI, 0ULL, nullptr, nullptr, act, SI);
  down_kernel<false><<<dim3(HD / 128, NTOK / 128, 1), blk, 0, stream>>>(
      act, SI, s_d, 0ULL, SI, nullptr, nullptr, nullptr, out_final);

  // text experts (modality 0) — atomic accumulate into out_final
  up_kernel<true><<<dim3(TI / 64, CAP / 128, NEXP), blk, 0, stream>>>(
      X, t_gu, t_gu + TI, 2 * TI, (unsigned long long)HD * 2 * TI,
      counts, disp, act, TI);
  down_kernel<true><<<dim3(HD / 128, CAP / 128, NEXP), blk, 0, stream>>>(
      act, TI, t_dn, (unsigned long long)TI * HD, TI,
      counts, disp, dispw, out_final);

  // vis experts (modality 1)
  up_kernel<true><<<dim3(VI / 64, CAP / 128, NEXP), blk, 0, stream>>>(
      X, v_gu, v_gu + VI, 2 * VI, (unsigned long long)HD * 2 * VI,
      counts + NEXP, disp + NEXP * CAP, act, VI);
  down_kernel<true><<<dim3(HD / 128, CAP / 128, NEXP), blk, 0, stream>>>(
      act, VI, v_dn, (unsigned long long)VI * HD, VI,
      counts + NEXP, disp + NEXP * CAP, dispw + NEXP * CAP, out_final);

  (void)in_sizes; (void)n_in; (void)out_size; (void)ws_size;
}